// Round 1
// 215.233 us; speedup vs baseline: 1.0341x; 1.0341x over previous
//
#include <hip/hip_runtime.h>
#include <math.h>

// SplashEncoding: 16-level hash grid, trilinear interp; levels 14/15 add
// Gaussian splash mixtures (ns=2/4) feeding both feature and GMM outputs.
//
// R9 vs R8 (main 139.8us, 2.28 cyc/lane-load; VALU 16%, HBM 18%):
//  - Theory: not at the gather wall — at the L2-capacity wall. Random hot set
//    was 18.4MB/XCD vs 4MB L2 -> ~50 line misses/pt served by Infinity Cache
//    (the extra ~1.1 cyc/load). FETCH_SIZE 138MB = one full table copy per XCD.
//  - Fix: plain hashed tables (levels 4-13, 80/96 random touches/pt) and
//    linear tables (levels 0-3) go fp16 -> fp8 e4m3 (OCP, HW cvt_pk).
//    Values pre-scaled x16 at repack (feats ~0.01*N(0,1) would sit in e4m3
//    denormal range); decode folds x1/16 into the final accumulate.
//    Hot set 6.4MB -> 3.2MB < 4MB/XCD -> plain+linear become L2-resident.
//  - Splash levels 14/15 stay fp16 (geometry precision; only 16 touches/pt).
//  - Load instruction count unchanged (144/pt); fp8 decode (1 cvt_pk) is
//    cheaper than 2x cvt_f32_f16.
//  - Everything else kept: phase/cache separation (R5), split-across-threads
//    work (R6/R7), precomputed reciprocals (R4), full-line writes (R3).

#define HMASK 131071
typedef float vf4 __attribute__((ext_vector_type(4)));
typedef float vf2 __attribute__((ext_vector_type(2)));
typedef _Float16 h8 __attribute__((ext_vector_type(8)));
typedef unsigned short u16;
typedef unsigned int u32;

// ws byte layout:
//   [0, 2621440)            : levels 4-13 fp8 tables (131072 entries x 2B each)
//   [2621440, 3343708)      : linear levels 0-3 fp8 PAIR table (entry idx ->
//                             {f[idx].xy, f[idx+1].xy} as 4 x fp8 = 1 dword)
//   [3670016, 7864320)      : L14 slots (32B each)
//   [7864320, 16252928)     : L15 slots (64B each)
#define LIN_OFF 2621440
#define L14_OFF 3670016
#define L15_OFF 7864320

// fbases (float2 rows) of hashed plain levels 4..13 (for repack + fallback)
__constant__ int c_fbh[10] = {180567,311639,442711,573783,704855,835927,
                              966999,1098071,1229143,1360215};
// pop0 per-q: linear levels 0..3, hashed levels 4..7
__constant__ int c_lres[4] = {16,23,34,50};
__constant__ int c_lfb[4]  = {0,4096,16263,55567};
__constant__ int c_h0res[4] = {74,109,161,237};
// pop1 per-q: levels 8+q and 11+q
__constant__ int c_p1resA[3] = {348,512,753};
__constant__ int c_p1resB[3] = {1108,1629,2394};

__device__ __forceinline__ void corner_setup(int res, float cx, float cy, float cz,
                                             int& px, int& py, int& pz,
                                             float& fx, float& fy, float& fz)
{
    const float hi = (float)res - 1.001f;            // matches jnp.clip(res*c, 0, res-1.001)
    float x = fminf(fmaxf((float)res * cx, 0.0f), hi);
    float y = fminf(fmaxf((float)res * cy, 0.0f), hi);
    float z = fminf(fmaxf((float)res * cz, 0.0f), hi);
    px = (int)x; py = (int)y; pz = (int)z;           // >=0 so trunc == floor
    fx = x - (float)px; fy = y - (float)py; fz = z - (float)pz;
}

// ---- fp32 fallback paths (workspace too small) --------------------------

__device__ __forceinline__ float2 linear_eval4(
    int res, int fbase, float cx, float cy, float cz,
    const float* __restrict__ feats)
{
    int px, py, pz; float fx, fy, fz;
    corner_setup(res, cx, cy, cz, px, py, pz, fx, fy, fz);
    int idxs[4]; float wyz[4];
#pragma unroll
    for (int j = 0; j < 4; ++j) {
        const int oy = (j >> 1) & 1, oz = j & 1;
        idxs[j] = px + (py + oy) * res + (pz + oz) * res * res;
        wyz[j] = (oy ? fy : 1.0f - fy) * (oz ? fz : 1.0f - fz);
    }
    vf4 fv[4];
#pragma unroll
    for (int j = 0; j < 4; ++j)
        fv[j] = *(const vf4*)(feats + (size_t)(fbase + idxs[j]) * 2);
    float a0 = 0.0f, a1 = 0.0f;
    const float gx = 1.0f - fx;
#pragma unroll
    for (int j = 0; j < 4; ++j) {
        a0 += wyz[j] * (gx * fv[j].x + fx * fv[j].z);
        a1 += wyz[j] * (gx * fv[j].y + fx * fv[j].w);
    }
    return make_float2(a0, a1);
}

__device__ __forceinline__ float2 plain_eval_f32h(
    int res, int fbase, float cx, float cy, float cz,
    const float* __restrict__ feats)
{
    int px, py, pz; float fx, fy, fz;
    corner_setup(res, cx, cy, cz, px, py, pz, fx, fy, fz);
    int   idxs[8];
    float ws[8];
#pragma unroll
    for (int k = 0; k < 8; ++k) {
        const int ox = (k >> 2) & 1, oy = (k >> 1) & 1, oz = k & 1;
        const int ix = px + ox, iy = py + oy, iz = pz + oz;
        ws[k] = (ox ? fx : 1.0f - fx) * (oy ? fy : 1.0f - fy) * (oz ? fz : 1.0f - fz);
        unsigned h = (unsigned)ix ^ ((unsigned)iy * 2654435761u) ^ ((unsigned)iz * 805459861u);
        idxs[k] = (int)(h & HMASK);
    }
    float2 fv[8];
#pragma unroll
    for (int k = 0; k < 8; ++k)
        fv[k] = *(const float2*)(feats + (size_t)(fbase + idxs[k]) * 2);
    float a0 = 0.0f, a1 = 0.0f;
#pragma unroll
    for (int k = 0; k < 8; ++k) { a0 += ws[k] * fv[k].x; a1 += ws[k] * fv[k].y; }
    return make_float2(a0, a1);
}

// ---- fp8 packed paths ----------------------------------------------------

// linear level, fp8 pair table: one dword load covers the ox=0/1 corner pair.
// Stored values are 16x; fold 1/16 into the return.
__device__ __forceinline__ float2 linear_eval4_fp8(
    int res, int ebase, float cx, float cy, float cz,
    const u32* __restrict__ ltab)
{
    int px, py, pz; float fx, fy, fz;
    corner_setup(res, cx, cy, cz, px, py, pz, fx, fy, fz);
    int idxs[4]; float wyz[4];
#pragma unroll
    for (int j = 0; j < 4; ++j) {
        const int oy = (j >> 1) & 1, oz = j & 1;
        idxs[j] = px + (py + oy) * res + (pz + oz) * res * res;
        wyz[j] = (oy ? fy : 1.0f - fy) * (oz ? fz : 1.0f - fz);
    }
    u32 u[4];
#pragma unroll
    for (int j = 0; j < 4; ++j) u[j] = ltab[ebase + idxs[j]];
    float a0 = 0.0f, a1 = 0.0f;
    const float gx = 1.0f - fx;
#pragma unroll
    for (int j = 0; j < 4; ++j) {
        vf2 lo = __builtin_amdgcn_cvt_pk_f32_fp8((int)u[j], false);  // ox=0
        vf2 hi = __builtin_amdgcn_cvt_pk_f32_fp8((int)u[j], true);   // ox=1
        a0 += wyz[j] * (gx * lo.x + fx * hi.x);
        a1 += wyz[j] * (gx * lo.y + fx * hi.y);
    }
    return make_float2(a0 * 0.0625f, a1 * 0.0625f);
}

// hashed plain level, fp8 table (2B/entry). Stored values are 16x.
__device__ __forceinline__ float2 plain_eval_fp8(
    int res, const u16* __restrict__ tab, float cx, float cy, float cz)
{
    int px, py, pz; float fx, fy, fz;
    corner_setup(res, cx, cy, cz, px, py, pz, fx, fy, fz);
    int   idxs[8];
    float ws[8];
#pragma unroll
    for (int k = 0; k < 8; ++k) {
        const int ox = (k >> 2) & 1, oy = (k >> 1) & 1, oz = k & 1;
        const int ix = px + ox, iy = py + oy, iz = pz + oz;
        ws[k] = (ox ? fx : 1.0f - fx) * (oy ? fy : 1.0f - fy) * (oz ? fz : 1.0f - fz);
        unsigned h = (unsigned)ix ^ ((unsigned)iy * 2654435761u) ^ ((unsigned)iz * 805459861u);
        idxs[k] = (int)(h & HMASK);
    }
    u16 v[8];
#pragma unroll
    for (int k = 0; k < 8; ++k) v[k] = tab[idxs[k]];
    float a0 = 0.0f, a1 = 0.0f;
#pragma unroll
    for (int k = 0; k < 8; ++k) {
        vf2 d = __builtin_amdgcn_cvt_pk_f32_fp8((int)v[k], false);
        a0 += ws[k] * d.x; a1 += ws[k] * d.y;
    }
    return make_float2(a0 * 0.0625f, a1 * 0.0625f);
}

// ---- splash (fp16 packed) ------------------------------------------------

__device__ __forceinline__ void gauss_pre(float w, float dx, float dy, float dz,
                                          float i2s, float inrm, float is2,
                                          float f0, float f1,
                                          float& a0, float& a1, float& ag)
{
    const float d2 = dx*dx + dy*dy + dz*dz;
    const float sq = d2 * i2s;
    const float gw = __expf(-sq) * inrm;
    const float wg = w * gw;
    a0 += wg * f0;
    a1 += wg * f1;
    ag += wg * (d2 * is2);
}

// L14 packed slot (32B = 2 h8):
//   A: mo0.xyz mo1.xyz i2s0 i2s1      B: inrm0 inrm1 is20 is21 f00 f01 f10 f11
// corners [k0, k0+2)
__device__ __forceinline__ void splash14_part(
    int k0, float cx, float cy, float cz, float cox, float coy, float coz,
    const h8* __restrict__ slots, float& a0, float& a1, float& ag)
{
    int px, py, pz; float fx, fy, fz;
    corner_setup(3520, cx, cy, cz, px, py, pz, fx, fy, fz);
    a0 = 0.0f; a1 = 0.0f; ag = 0.0f;
#pragma unroll
    for (int kk = 0; kk < 2; ++kk) {
        const int k = k0 + kk;
        const int ox = (k >> 2) & 1, oy = (k >> 1) & 1, oz = k & 1;
        const int ix = px + ox, iy = py + oy, iz = pz + oz;
        const float w = (ox ? fx : 1.0f - fx) * (oy ? fy : 1.0f - fy) * (oz ? fz : 1.0f - fz);
        unsigned h = (unsigned)ix ^ ((unsigned)iy * 2654435761u) ^ ((unsigned)iz * 805459861u);
        const int idx = (int)(h & HMASK);
        const h8* sp = slots + (size_t)idx * 2;
        h8 A = sp[0], B = sp[1];
        gauss_pre(w, cox - (float)A[0], coy - (float)A[1], coz - (float)A[2],
                  (float)A[6], (float)B[0], (float)B[2], (float)B[4], (float)B[5], a0, a1, ag);
        gauss_pre(w, cox - (float)A[3], coy - (float)A[4], coz - (float)A[5],
                  (float)A[7], (float)B[1], (float)B[3], (float)B[6], (float)B[7], a0, a1, ag);
    }
}

// L15 packed slot (64B = 4 h8 = ONE cache line):
//   A: mo[0..7]   B: mo[8..11] i2s[0..3]   C: inrm[0..3] is2[0..3]   D: f[0..7]
// single corner k
__device__ __forceinline__ void splash15_part(
    int k, float cx, float cy, float cz, float cox, float coy, float coz,
    const h8* __restrict__ slots, float& a0, float& a1, float& ag)
{
    int px, py, pz; float fx, fy, fz;
    corner_setup(5174, cx, cy, cz, px, py, pz, fx, fy, fz);
    a0 = 0.0f; a1 = 0.0f; ag = 0.0f;
    const int ox = (k >> 2) & 1, oy = (k >> 1) & 1, oz = k & 1;
    const int ix = px + ox, iy = py + oy, iz = pz + oz;
    const float w = (ox ? fx : 1.0f - fx) * (oy ? fy : 1.0f - fy) * (oz ? fz : 1.0f - fz);
    unsigned h = (unsigned)ix ^ ((unsigned)iy * 2654435761u) ^ ((unsigned)iz * 805459861u);
    const int idx = (int)(h & HMASK);
    const h8* sp = slots + (size_t)idx * 4;
    h8 A = sp[0], B = sp[1], C = sp[2], D = sp[3];
    gauss_pre(w, cox - (float)A[0], coy - (float)A[1], coz - (float)A[2],
              (float)B[4], (float)C[0], (float)C[4], (float)D[0], (float)D[1], a0, a1, ag);
    gauss_pre(w, cox - (float)A[3], coy - (float)A[4], coz - (float)A[5],
              (float)B[5], (float)C[1], (float)C[5], (float)D[2], (float)D[3], a0, a1, ag);
    gauss_pre(w, cox - (float)A[6], coy - (float)A[7], coz - (float)B[0],
              (float)B[6], (float)C[2], (float)C[6], (float)D[4], (float)D[5], a0, a1, ag);
    gauss_pre(w, cox - (float)B[1], coy - (float)B[2], coz - (float)B[3],
              (float)B[7], (float)C[3], (float)C[7], (float)D[6], (float)D[7], a0, a1, ag);
}

// fallback splash (direct fp32 table loads), corner range [k0, k0+KN)
template<int NS, int KN>
__device__ __forceinline__ void splash_direct_part(
    int k0, int res, int fbase, int gbase, float cx, float cy, float cz,
    const float* __restrict__ feats, const float* __restrict__ means,
    const float* __restrict__ stds, float& a0, float& a1, float& ag)
{
    int px, py, pz; float fx, fy, fz;
    corner_setup(res, cx, cy, cz, px, py, pz, fx, fy, fz);
    a0 = 0.0f; a1 = 0.0f; ag = 0.0f;
#pragma unroll
    for (int kk = 0; kk < KN; ++kk) {
        const int k = k0 + kk;
        const int ox = (k >> 2) & 1, oy = (k >> 1) & 1, oz = k & 1;
        const int ix = px + ox, iy = py + oy, iz = pz + oz;
        const float w = (ox ? fx : 1.0f - fx) * (oy ? fy : 1.0f - fy) * (oz ? fz : 1.0f - fz);
        unsigned h = (unsigned)ix ^ ((unsigned)iy * 2654435761u) ^ ((unsigned)iz * 805459861u);
        const int idx = (int)(h & HMASK);
        const int grow = gbase + idx * NS;
        const float* m = means + (size_t)grow * 3;
        const float* s = stds + grow;
        const float* f = feats + (size_t)(fbase + idx * NS) * 2;
#pragma unroll
        for (int si = 0; si < NS; ++si) {
            const float dx = cx - m[3*si], dy = cy - m[3*si+1], dz = cz - m[3*si+2];
            const float sva = fabsf(s[si]);
            const float d2 = dx*dx + dy*dy + dz*dz;
            const float s2 = sva * sva;
            const float sq = d2 / (2.0f * s2 + 1e-7f);
            const float gw = expf(-sq) / (2.5066282746310002f * sva + 1e-7f);
            const float wg = w * gw;
            a0 += wg * f[2*si];
            a1 += wg * f[2*si+1];
            ag += wg * (d2 / s2);
        }
    }
}

// repack threads (by block range):
//   [0,640)     plain levels 4-13 -> fp8, 8 entries/thread (16384 thr/level)
//   [640,1346)  linear pair table -> fp8, 1 entry/thread (180567 entries)
//   [1346,1858) L14 slots (131072)
//   [1858,2370) L15 slots (131072)
__global__ __launch_bounds__(256) void repack_kernel(
    const float* __restrict__ means, const float* __restrict__ stds,
    const float* __restrict__ feats, unsigned char* __restrict__ wsb)
{
    const int b = blockIdx.x;
    const int tid = threadIdx.x;
    if (b < 640) {
        const int j   = b * 256 + tid;      // 0..163839
        const int lvl = j >> 14;            // /16384
        const int e8  = (j & 16383) * 8;    // entry base, 8 entries/thread
        const float* src = feats + (size_t)(c_fbh[lvl] + e8) * 2;
        uint4 u;
        u32* up = (u32*)&u;
#pragma unroll
        for (int p = 0; p < 4; ++p) {       // 2 entries per dword
            vf4 f = *(const vf4*)(src + 4 * p);
            int w = __builtin_amdgcn_cvt_pk_fp8_f32(16.0f * f.x, 16.0f * f.y, 0, false);
            w = __builtin_amdgcn_cvt_pk_fp8_f32(16.0f * f.z, 16.0f * f.w, w, true);
            up[p] = (u32)w;
        }
        *(uint4*)(wsb + (size_t)lvl * 262144 + (size_t)e8 * 2) = u;   // 16B aligned
    } else if (b < 1346) {
        const int e = (b - 640) * 256 + tid;
        if (e < 180567) {
            // pair table: entry e holds {f[e].xy, f[e+1].xy}; f[e+1] read is
            // always in-bounds (feats continues into hashed-level rows).
            const float2 fa = *(const float2*)(feats + 2 * (size_t)e);
            const float2 fb = *(const float2*)(feats + 2 * (size_t)e + 2);
            int w = __builtin_amdgcn_cvt_pk_fp8_f32(16.0f * fa.x, 16.0f * fa.y, 0, false);
            w = __builtin_amdgcn_cvt_pk_fp8_f32(16.0f * fb.x, 16.0f * fb.y, w, true);
            ((u32*)(wsb + LIN_OFF))[e] = (u32)w;
        }
    } else if (b < 1858) {
        // level 14: ns=2, gbase=0, fbase=1491287
        const int e = (b - 1346) * 256 + tid;
        const float2* m2 = (const float2*)(means + (size_t)e * 6);
        const float2 ma = m2[0], mb = m2[1], mc = m2[2];
        const float2 sv = *(const float2*)(stds + 2 * e);
        const float2* f2 = (const float2*)(feats + (size_t)(1491287 + 2 * e) * 2);
        const float2 fa = f2[0], fb = f2[1];
        const float s0 = fabsf(sv.x), s1 = fabsf(sv.y);
        h8 A, B;
        A[0] = (_Float16)(ma.x - 0.5f); A[1] = (_Float16)(ma.y - 0.5f); A[2] = (_Float16)(mb.x - 0.5f);
        A[3] = (_Float16)(mb.y - 0.5f); A[4] = (_Float16)(mc.x - 0.5f); A[5] = (_Float16)(mc.y - 0.5f);
        A[6] = (_Float16)(1.0f / (2.0f * s0 * s0 + 1e-7f));
        A[7] = (_Float16)(1.0f / (2.0f * s1 * s1 + 1e-7f));
        B[0] = (_Float16)(1.0f / (2.5066282746310002f * s0 + 1e-7f));
        B[1] = (_Float16)(1.0f / (2.5066282746310002f * s1 + 1e-7f));
        B[2] = (_Float16)(1.0f / (s0 * s0));
        B[3] = (_Float16)(1.0f / (s1 * s1));
        B[4] = (_Float16)fa.x; B[5] = (_Float16)fa.y; B[6] = (_Float16)fb.x; B[7] = (_Float16)fb.y;
        h8* dst = (h8*)(wsb + L14_OFF) + (size_t)e * 2;
        dst[0] = A; dst[1] = B;
    } else {
        // level 15: ns=4, gbase=262144, fbase=1753431
        const int e = (b - 1858) * 256 + tid;
        const vf4* m4 = (const vf4*)(means + (size_t)(262144 + 4 * e) * 3);
        const vf4 u = m4[0], v = m4[1], w = m4[2];
        const vf4 s4 = *(const vf4*)(stds + 262144 + 4 * e);
        const float2* f2 = (const float2*)(feats + (size_t)(1753431 + 4 * e) * 2);
        const float2 fa = f2[0], fb = f2[1], fc = f2[2], fd = f2[3];
        h8 A, B, C, D;
        A[0] = (_Float16)(u.x - 0.5f); A[1] = (_Float16)(u.y - 0.5f); A[2] = (_Float16)(u.z - 0.5f);
        A[3] = (_Float16)(u.w - 0.5f); A[4] = (_Float16)(v.x - 0.5f); A[5] = (_Float16)(v.y - 0.5f);
        A[6] = (_Float16)(v.z - 0.5f); A[7] = (_Float16)(v.w - 0.5f);
        B[0] = (_Float16)(w.x - 0.5f); B[1] = (_Float16)(w.y - 0.5f);
        B[2] = (_Float16)(w.z - 0.5f); B[3] = (_Float16)(w.w - 0.5f);
        const float sv[4] = {fabsf(s4.x), fabsf(s4.y), fabsf(s4.z), fabsf(s4.w)};
#pragma unroll
        for (int t = 0; t < 4; ++t) {
            B[4 + t] = (_Float16)(1.0f / (2.0f * sv[t] * sv[t] + 1e-7f));
            C[t]     = (_Float16)(1.0f / (2.5066282746310002f * sv[t] + 1e-7f));
            C[4 + t] = (_Float16)(1.0f / (sv[t] * sv[t]));
        }
        D[0] = (_Float16)fa.x; D[1] = (_Float16)fa.y; D[2] = (_Float16)fb.x; D[3] = (_Float16)fb.y;
        D[4] = (_Float16)fc.x; D[5] = (_Float16)fc.y; D[6] = (_Float16)fd.x; D[7] = (_Float16)fd.y;
        h8* dst = (h8*)(wsb + L15_OFF) + (size_t)e * 4;
        dst[0] = A; dst[1] = B; dst[2] = C; dst[3] = D;
    }
}

// grid: [0,4096) pop0 lv0-7 4thr/pt | [4096,7168) pop1 lv8-13 3thr/pt |
//       [7168,11264) L14 4thr/pt | [11264,19456) L15 8thr/pt
template<bool PACKED>
__global__ __launch_bounds__(256) void splash_enc(
    const float* __restrict__ coords, const float* __restrict__ feats,
    const float* __restrict__ means,  const float* __restrict__ stds,
    const unsigned char* __restrict__ wsb, float* __restrict__ out, int N)
{
    const int b = blockIdx.x;
    const int tid = threadIdx.x;
    const u16* ptab = (const u16*)wsb;                 // plain fp8: level L in [4,13] -> + (L-4)*131072
    const u32* ltab = (const u32*)(wsb + LIN_OFF);     // linear fp8 pair table
    float* gmm = out + (size_t)N * 32;

    if (b < 4096) {
        // ---- pop0: levels 0-7, thread q: linear level q + hashed level q+4
        const int t = b * 256 + tid;
        const int n = t >> 2, q = t & 3;
        const float cx = coords[3*n+0], cy = coords[3*n+1], cz = coords[3*n+2];
        float2 rlin, rhsh;
        if (PACKED) {
            rlin = linear_eval4_fp8(c_lres[q], c_lfb[q], cx, cy, cz, ltab);
            rhsh = plain_eval_fp8(c_h0res[q], ptab + q * 131072, cx, cy, cz);
        } else {
            rlin = linear_eval4(c_lres[q], c_lfb[q], cx, cy, cz, feats);
            rhsh = plain_eval_f32h(c_h0res[q], c_fbh[q], cx, cy, cz, feats);
        }
        *(float2*)(out + (size_t)n * 32 + 2 * q)     = rlin;
        *(float2*)(out + (size_t)n * 32 + 8 + 2 * q) = rhsh;
    } else if (b < 7168) {
        // ---- pop1: levels 8-13, thread q: levels 8+q and 11+q
        const int t = (b - 4096) * 256 + tid;               // [0, 786432)
        const int n = (int)(((unsigned long long)(unsigned)t * 0xAAAAAAABull) >> 33);
        const int q = t - 3 * n;
        const float cx = coords[3*n+0], cy = coords[3*n+1], cz = coords[3*n+2];
        float2 rA, rB;
        if (PACKED) {
            rA = plain_eval_fp8(c_p1resA[q], ptab + (4 + q) * 131072, cx, cy, cz);
            rB = plain_eval_fp8(c_p1resB[q], ptab + (7 + q) * 131072, cx, cy, cz);
        } else {
            rA = plain_eval_f32h(c_p1resA[q], c_fbh[4 + q], cx, cy, cz, feats);
            rB = plain_eval_f32h(c_p1resB[q], c_fbh[7 + q], cx, cy, cz, feats);
        }
        *(float2*)(out + (size_t)n * 32 + 16 + 2 * q) = rA;
        *(float2*)(out + (size_t)n * 32 + 22 + 2 * q) = rB;
    } else if (b < 11264) {
        // ---- L14: 4 threads/point, 2 corners each
        const int t = (b - 7168) * 256 + tid;
        const int n = t >> 2, q = t & 3;
        const float cx = coords[3*n+0], cy = coords[3*n+1], cz = coords[3*n+2];
        float a0, a1, ag;
        if (PACKED) {
            splash14_part(q * 2, cx, cy, cz, cx - 0.5f, cy - 0.5f, cz - 0.5f,
                          (const h8*)(wsb + L14_OFF), a0, a1, ag);
        } else {
            splash_direct_part<2,2>(q * 2, 3520, 1491287, 0, cx, cy, cz,
                                    feats, means, stds, a0, a1, ag);
        }
        a0 += __shfl_xor(a0, 1); a1 += __shfl_xor(a1, 1); ag += __shfl_xor(ag, 1);
        a0 += __shfl_xor(a0, 2); a1 += __shfl_xor(a1, 2); ag += __shfl_xor(ag, 2);
        if (q == 0) {
            *(float2*)(out + (size_t)n * 32 + 28) = make_float2(a0, a1);
            gmm[2 * n] = ag;
        }
    } else {
        // ---- L15: 8 threads/point, 1 corner each
        const int t = (b - 11264) * 256 + tid;
        const int n = t >> 3, q = t & 7;
        const float cx = coords[3*n+0], cy = coords[3*n+1], cz = coords[3*n+2];
        float a0, a1, ag;
        if (PACKED) {
            splash15_part(q, cx, cy, cz, cx - 0.5f, cy - 0.5f, cz - 0.5f,
                          (const h8*)(wsb + L15_OFF), a0, a1, ag);
        } else {
            splash_direct_part<4,1>(q, 5174, 1753431, 262144, cx, cy, cz,
                                    feats, means, stds, a0, a1, ag);
        }
        a0 += __shfl_xor(a0, 1); a1 += __shfl_xor(a1, 1); ag += __shfl_xor(ag, 1);
        a0 += __shfl_xor(a0, 2); a1 += __shfl_xor(a1, 2); ag += __shfl_xor(ag, 2);
        a0 += __shfl_xor(a0, 4); a1 += __shfl_xor(a1, 4); ag += __shfl_xor(ag, 4);
        if (q == 0) {
            *(float2*)(out + (size_t)n * 32 + 30) = make_float2(a0, a1);
            gmm[2 * n + 1] = ag;
        }
    }
}

extern "C" void kernel_launch(void* const* d_in, const int* in_sizes, int n_in,
                              void* d_out, int out_size, void* d_ws, size_t ws_size,
                              hipStream_t stream) {
    const float* coords = (const float*)d_in[0];
    const float* feats  = (const float*)d_in[1];
    const float* means  = (const float*)d_in[2];
    const float* stds   = (const float*)d_in[3];
    float* out = (float*)d_out;
    const int N = in_sizes[0] / 3;   // 262144

    const bool packed = (ws_size >= 17825792);   // need 15.5MB; keep old gate
    if (packed) {
        repack_kernel<<<2370, 256, 0, stream>>>(means, stds, feats, (unsigned char*)d_ws);
        splash_enc<true><<<19456, 256, 0, stream>>>(coords, feats, means, stds,
                                                    (const unsigned char*)d_ws, out, N);
    } else {
        splash_enc<false><<<19456, 256, 0, stream>>>(coords, feats, means, stds,
                                                     (const unsigned char*)d_ws, out, N);
    }
}